// Round 10
// baseline (169.459 us; speedup 1.0000x reference)
//
#include <hip/hip_runtime.h>

#define DIMD 512
#define NTOK 2048
#define HEADS 8
#define DH 64

typedef __attribute__((ext_vector_type(4))) float f32x4;
typedef __attribute__((ext_vector_type(8))) __bf16 bf16x8;
typedef __attribute__((ext_vector_type(4))) short s16x4;

#define MFMA16(a, b, c) __builtin_amdgcn_mfma_f32_16x16x32_bf16((a), (b), (c), 0, 0, 0)
#define MFMAK16(a, b, c) __builtin_amdgcn_mfma_f32_16x16x16bf16_1k((a), (b), (c), 0, 0, 0)

// partial-drain barrier: wait until <=N of this wave's vm ops outstanding, then barrier.
// All waves execute identical DMA counts -> after barrier, tile data from ALL waves is in LDS.
#define WAIT_BAR(N) asm volatile("s_waitcnt vmcnt(" #N ")\n\ts_barrier" ::: "memory")

__device__ __forceinline__ unsigned short f2bf(float f) {
  unsigned int u = __float_as_uint(f);
  u += 0x7fffu + ((u >> 16) & 1u);
  return (unsigned short)(u >> 16);
}

// pack truncated bf16(b) into low short, bf16(a) into high short
__device__ __forceinline__ unsigned packhi(float b, float a) {
#if __has_builtin(__builtin_amdgcn_perm)
  return __builtin_amdgcn_perm(__float_as_uint(a), __float_as_uint(b), 0x07060302u);
#else
  return (__float_as_uint(b) >> 16) | (__float_as_uint(a) & 0xffff0000u);
#endif
}

// async global->LDS, 16B per lane; LDS dest = wave base + lane*16 (contiguous).
__device__ __forceinline__ void gl2lds16(const void* g, void* l) {
  auto gp = reinterpret_cast<__attribute__((address_space(1))) unsigned int*>(
      reinterpret_cast<unsigned long long>(g));
  auto lp = reinterpret_cast<__attribute__((address_space(3))) unsigned int*>(
      reinterpret_cast<unsigned long long>(l));
  __builtin_amdgcn_global_load_lds(gp, lp, 16, 0, 0);
}

// ---------------- prep: LN(bid<2048) + w_qkv transpose + w_out transpose ----------------
__global__ __launch_bounds__(256) void prep_kernel(const float* __restrict__ x,
                                                   const float* __restrict__ gamma,
                                                   const float* __restrict__ beta,
                                                   const float* __restrict__ w_qkv,
                                                   const float* __restrict__ w_out,
                                                   unsigned short* __restrict__ xn,
                                                   unsigned short* __restrict__ wqkvT,
                                                   unsigned short* __restrict__ woutT) {
  __shared__ float t[32][33];
  const int bid = blockIdx.x;
  if (bid < 2048) {
    const int row = bid * 4 + (threadIdx.x >> 6);
    const int lane = threadIdx.x & 63;
    const float4* xr = (const float4*)(x + (size_t)row * DIMD);
    float4 a = xr[lane];
    float4 b = xr[lane + 64];
    float s = a.x + a.y + a.z + a.w + b.x + b.y + b.z + b.w;
    for (int off = 1; off < 64; off <<= 1) s += __shfl_xor(s, off, 64);
    float mu = s * (1.0f / DIMD);
    float d0 = a.x - mu, d1 = a.y - mu, d2 = a.z - mu, d3 = a.w - mu;
    float e0 = b.x - mu, e1 = b.y - mu, e2 = b.z - mu, e3 = b.w - mu;
    float v = d0 * d0 + d1 * d1 + d2 * d2 + d3 * d3 + e0 * e0 + e1 * e1 + e2 * e2 + e3 * e3;
    for (int off = 1; off < 64; off <<= 1) v += __shfl_xor(v, off, 64);
    float rs = rsqrtf(v * (1.0f / DIMD) + 1e-5f);
    const float4* g4 = (const float4*)gamma;
    const float4* be4 = (const float4*)beta;
    float4 ga = g4[lane], gb = g4[lane + 64];
    float4 ba = be4[lane], bb = be4[lane + 64];
    unsigned p0 = (unsigned)f2bf(d0 * rs * ga.x + ba.x) | ((unsigned)f2bf(d1 * rs * ga.y + ba.y) << 16);
    unsigned p1 = (unsigned)f2bf(d2 * rs * ga.z + ba.z) | ((unsigned)f2bf(d3 * rs * ga.w + ba.w) << 16);
    unsigned p2 = (unsigned)f2bf(e0 * rs * gb.x + bb.x) | ((unsigned)f2bf(e1 * rs * gb.y + bb.y) << 16);
    unsigned p3 = (unsigned)f2bf(e2 * rs * gb.z + bb.z) | ((unsigned)f2bf(e3 * rs * gb.w + bb.w) << 16);
    uint2 w0; w0.x = p0; w0.y = p1;
    uint2 w1; w1.x = p2; w1.y = p3;
    *(uint2*)&xn[(size_t)row * DIMD + lane * 4] = w0;
    *(uint2*)&xn[(size_t)row * DIMD + 256 + lane * 4] = w1;
  } else {
    const float* w;
    unsigned short* wt;
    int C, bx, by;
    if (bid < 2816) { w = w_qkv; wt = wqkvT; C = 1536; bx = (bid - 2048) % 48; by = (bid - 2048) / 48; }
    else            { w = w_out; wt = woutT; C = 512;  bx = (bid - 2816) % 16; by = (bid - 2816) / 16; }
    const int R = 512;
    int tx = threadIdx.x & 31, ty = threadIdx.x >> 5;
    int c0 = bx * 32, r0 = by * 32;
    for (int i = 0; i < 4; i++)
      t[ty + 8 * i][tx] = w[(size_t)(r0 + ty + 8 * i) * C + c0 + tx];
    __syncthreads();
    for (int i = 0; i < 4; i++)
      wt[(size_t)(c0 + ty + 8 * i) * R + r0 + tx] = f2bf(t[tx][ty + 8 * i]);
  }
}

// ---------------- QKV GEMM: 128x128 tile, BK=64, triple-buf dist-2 prefetch ----------------
__global__ __launch_bounds__(256) void qkv_gemm(const unsigned short* __restrict__ A,
                                                const unsigned short* __restrict__ Bt,
                                                unsigned short* __restrict__ qb,
                                                unsigned short* __restrict__ kb,
                                                unsigned short* __restrict__ vtb) {
  __shared__ unsigned short As[3][128 * 64];
  __shared__ unsigned short Bs[3][128 * 64];
  const int tid = threadIdx.x;
  const int wave = tid >> 6, lane = tid & 63;
  const int row16 = lane & 15, quad = lane >> 4;
  const int rho = row16 & 7;
  const int m0 = blockIdx.x * 128;
  const int n0 = blockIdx.y * 128;
  const int rw = (wave & 1) * 64, cw = (wave >> 1) * 64;

  const char* Ab = (const char*)A;
  const char* Bb = (const char*)Bt;
  // prologue: k-tiles 0 and 1 (8 DMA instr each)
#pragma unroll
  for (int kt = 0; kt < 2; kt++)
#pragma unroll
    for (int i = 0; i < 4; i++) {
      int idx = i * 256 + tid;
      int r = idx >> 3;
      int c = (idx & 7) ^ (r & 7);
      gl2lds16(Ab + ((size_t)(m0 + r) * DIMD + kt * 64) * 2 + c * 16, (char*)As[kt] + idx * 16);
      gl2lds16(Bb + ((size_t)(n0 + r) * DIMD + kt * 64) * 2 + c * 16, (char*)Bs[kt] + idx * 16);
    }

  f32x4 acc[4][4] = {};
  for (int kt = 0; kt < 8; kt++) {
    if (kt == 7) WAIT_BAR(0); else WAIT_BAR(8);  // own tile-kt DMAs done; t+1,t+2 in flight
    if (kt < 6) {
      const int k0 = (kt + 2) * 64;
      const int buf2 = (kt + 2) % 3;
#pragma unroll
      for (int i = 0; i < 4; i++) {
        int idx = i * 256 + tid;
        int r = idx >> 3;
        int c = (idx & 7) ^ (r & 7);
        gl2lds16(Ab + ((size_t)(m0 + r) * DIMD + k0) * 2 + c * 16, (char*)As[buf2] + idx * 16);
        gl2lds16(Bb + ((size_t)(n0 + r) * DIMD + k0) * 2 + c * 16, (char*)Bs[buf2] + idx * 16);
      }
    }
    const int buf = kt % 3;
#pragma unroll
    for (int ks = 0; ks < 2; ks++) {
      bf16x8 av[4], bv[4];
#pragma unroll
      for (int i = 0; i < 4; i++) {
        int Ra = rw + i * 16 + row16;
        int Rb = cw + i * 16 + row16;
        av[i] = *(const bf16x8*)&As[buf][Ra * 64 + (((ks * 4 + quad) ^ rho) * 8)];
        bv[i] = *(const bf16x8*)&Bs[buf][Rb * 64 + (((ks * 4 + quad) ^ rho) * 8)];
      }
#pragma unroll
      for (int i = 0; i < 4; i++)
#pragma unroll
        for (int j = 0; j < 4; j++) acc[i][j] = MFMA16(av[i], bv[j], acc[i][j]);
    }
  }
  __syncthreads();

  unsigned short* Ct = (unsigned short*)As;
#pragma unroll
  for (int i = 0; i < 4; i++)
#pragma unroll
    for (int j = 0; j < 4; j++)
#pragma unroll
      for (int r = 0; r < 4; r++)
        Ct[(rw + i * 16 + quad * 4 + r) * 136 + cw + j * 16 + row16] = f2bf(acc[i][j][r]);
  __syncthreads();

  const int sect = n0 >> 9;
  const int h0 = (n0 & 511) >> 6;
  const int b = m0 >> 11;
  const int nbase = m0 & 2047;
  if (sect < 2) {
    unsigned short* dst = (sect == 0) ? qb : kb;
#pragma unroll
    for (int i = 0; i < 8; i++) {
      int cid = i * 256 + tid;
      int row = cid >> 4, col0 = (cid & 15) * 8;
      int h = h0 + (col0 >> 6), d0 = col0 & 63;
      uint4 val = *(const uint4*)&Ct[row * 136 + col0];
      *(uint4*)&dst[(((size_t)(b * HEADS + h) * NTOK) + nbase + row) * DH + d0] = val;
    }
  } else {
#pragma unroll
    for (int u = 0; u < 4; u++) {
      int uid = u * 256 + tid;
      int col = uid >> 3, rc = (uid & 7) * 16;
      int h = h0 + (col >> 6), d = col & 63;
      unsigned short tmp[16];
#pragma unroll
      for (int j = 0; j < 16; j++) tmp[j] = Ct[(rc + j) * 136 + col];
      size_t base = ((size_t)(b * HEADS + h) * DH + d) * NTOK + nbase + rc;
      *(uint4*)&vtb[base] = *(uint4*)&tmp[0];
      *(uint4*)&vtb[base + 8] = *(uint4*)&tmp[8];
    }
  }
}

// ---------------- attention: q-tile 256, triple-buf K/V, dist-2 prefetch, partial drains ----------------
__global__ __launch_bounds__(512) void attn_kernel(const unsigned short* __restrict__ qb,
                                                   const unsigned short* __restrict__ kb,
                                                   const unsigned short* __restrict__ vtb,
                                                   const int* __restrict__ mlab,
                                                   unsigned short* __restrict__ ao) {
  __shared__ unsigned short Qs[256 * 64];     // 32KB
  __shared__ unsigned short Ks[3][64 * 64];   // 24KB
  __shared__ unsigned short Vs[3][64 * 64];   // 24KB
  const int tid = threadIdx.x;
  const int wave = tid >> 6, lane = tid & 63;
  const int row16 = lane & 15, quad = lane >> 4;
  const int rho = row16 & 7;
  const int bh = blockIdx.y;
  const int b = bh >> 3, h = bh & 7;
  const int q0 = blockIdx.x * 256;

  const char* qg = (const char*)(qb + ((size_t)bh * NTOK + q0) * DH);
  const char* kgb = (const char*)(kb + (size_t)bh * NTOK * DH);
  const char* vgb = (const char*)(vtb + (size_t)bh * DH * NTOK);
  const int sr = tid >> 3;              // 0..63 staging row
  const int sc = (tid & 7) ^ (sr & 7);  // swizzled source chunk

  // prologue: Q (4 instr), then K0,V0,K1,V1 (FIFO order matters for vmcnt)
#pragma unroll
  for (int i = 0; i < 4; i++)
    gl2lds16(qg + (sr + 64 * i) * 128 + sc * 16, (char*)Qs + tid * 16 + i * 8192);
  gl2lds16(kgb + sr * 128 + sc * 16, (char*)Ks[0] + tid * 16);
  gl2lds16(vgb + (size_t)sr * 4096 + sc * 16, (char*)Vs[0] + tid * 16);
  gl2lds16(kgb + 8192 + sr * 128 + sc * 16, (char*)Ks[1] + tid * 16);
  gl2lds16(vgb + 128 + (size_t)sr * 4096 + sc * 16, (char*)Vs[1] + tid * 16);
  WAIT_BAR(4);  // Q (oldest 4) complete across all waves; K/V 0&1 still in flight

  // wave owns q-rows [wave*32, wave*32+32); Q region is never overwritten
  bf16x8 aq[2][2];
#pragma unroll
  for (int qs = 0; qs < 2; qs++) {
    const int qrow = wave * 32 + qs * 16 + row16;
#pragma unroll
    for (int ki = 0; ki < 2; ki++)
      aq[qs][ki] = *(const bf16x8*)&Qs[qrow * 64 + (((ki * 4 + quad) ^ rho) * 8)];
  }

  f32x4 accT[4][2] = {};  // O^T frags: [d-group][q-group]
  float lsum[2] = {0.f, 0.f};
  const float cs = 0.125f * 1.44269504088896f;
  const float c0 = mlab[b * 4 + 0] ? -16.f : -100000.f;
  const float c1 = mlab[b * 4 + 1] ? -16.f : -100000.f;
  const float c2 = mlab[b * 4 + 2] ? -16.f : -100000.f;
  const float c3 = mlab[b * 4 + 3] ? -16.f : -100000.f;

  for (int t = 0; t < 32; t++) {
    if (t == 31) WAIT_BAR(0); else WAIT_BAR(2);  // tile t ready everywhere; t+1 (2 ops) in flight
    if (t < 30) {  // issue t+2 into buffer (t+2)%3: its readers (tile t-1) done pre-barrier
      gl2lds16(kgb + (size_t)(t + 2) * 8192 + sr * 128 + sc * 16, (char*)Ks[(t + 2) % 3] + tid * 16);
      gl2lds16(vgb + (size_t)(t + 2) * 128 + (size_t)sr * 4096 + sc * 16, (char*)Vs[(t + 2) % 3] + tid * 16);
    }
    const int buf = t % 3;
    // S'[key][q]: A = K frag, B = Q frag
    f32x4 S[2][4];
#pragma unroll
    for (int f = 0; f < 4; f++) {
      const unsigned short* Kr = &Ks[buf][(f * 16 + row16) * 64];
      bf16x8 ak0 = *(const bf16x8*)&Kr[(quad ^ rho) * 8];
      bf16x8 ak1 = *(const bf16x8*)&Kr[((quad + 4) ^ rho) * 8];
#pragma unroll
      for (int qs = 0; qs < 2; qs++) {
        f32x4 z = {};
        z = MFMA16(ak0, aq[qs][0], z);
        z = MFMA16(ak1, aq[qs][1], z);
        S[qs][f] = z;
      }
    }
    const int mi = t >> 3;
    const float c = (mi == 0) ? c0 : (mi == 1) ? c1 : (mi == 2) ? c2 : c3;
    // P' = exp2(S'*cs + c); pack into K16 B-operand frags; lsum via VALU adds
    s16x4 pf[2][4];
#pragma unroll
    for (int qs = 0; qs < 2; qs++)
#pragma unroll
      for (int f = 0; f < 4; f++) {
        float p0 = exp2f(fmaf(S[qs][f][0], cs, c));
        float p1 = exp2f(fmaf(S[qs][f][1], cs, c));
        float p2 = exp2f(fmaf(S[qs][f][2], cs, c));
        float p3 = exp2f(fmaf(S[qs][f][3], cs, c));
        lsum[qs] += (p0 + p1) + (p2 + p3);
        uint2 pk;
        pk.x = packhi(p0, p1);
        pk.y = packhi(p2, p3);
        pf[qs][f] = *(s16x4*)&pk;
      }
    // O^T += V^T · P'
#pragma unroll
    for (int g = 0; g < 4; g++) {
      const unsigned short* Vr = &Vs[buf][(g * 16 + row16) * 64];
#pragma unroll
      for (int u = 0; u < 4; u++) {
        s16x4 va = *(const s16x4*)&Vr[(((2 * u + (quad >> 1)) ^ rho) * 8) + (quad & 1) * 4];
#pragma unroll
        for (int qs = 0; qs < 2; qs++) accT[g][qs] = MFMAK16(va, pf[qs][u], accT[g][qs]);
      }
    }
  }

  // lane partial covers its quad's keys; combine across quads (q = qs*16+row16)
#pragma unroll
  for (int qs = 0; qs < 2; qs++) {
    float s = lsum[qs];
    s += __shfl_xor(s, 16, 64);
    s += __shfl_xor(s, 32, 64);
    lsum[qs] = 1.0f / s;
  }
#pragma unroll
  for (int qs = 0; qs < 2; qs++) {
    const int q = q0 + wave * 32 + qs * 16 + row16;
    unsigned short* aor = ao + ((size_t)b * NTOK + q) * DIMD + h * DH;
#pragma unroll
    for (int g = 0; g < 4; g++) {
      *(unsigned*)&aor[g * 16 + quad * 4] = packhi(accT[g][qs][0] * lsum[qs], accT[g][qs][1] * lsum[qs]);
      *(unsigned*)&aor[g * 16 + quad * 4 + 2] = packhi(accT[g][qs][2] * lsum[qs], accT[g][qs][3] * lsum[qs]);
    }
  }
}

// ---------------- out GEMM: 128x64 tile, triple-buf dist-2 prefetch, fp32 out + bias ----------------
__global__ __launch_bounds__(256) void out_gemm(const unsigned short* __restrict__ A,
                                                const unsigned short* __restrict__ Bt,
                                                const float* __restrict__ bias,
                                                float* __restrict__ out) {
  __shared__ unsigned short As[3][128 * 64];
  __shared__ unsigned short Bs[3][64 * 64];
  const int tid = threadIdx.x;
  const int wave = tid >> 6, lane = tid & 63;
  const int row16 = lane & 15, quad = lane >> 4;
  const int rho = row16 & 7;
  const int m0 = blockIdx.x * 128;
  const int n0 = blockIdx.y * 64;
  const int rw = (wave & 1) * 64, cw = (wave >> 1) * 32;

  const char* Ab = (const char*)A;
  const char* Bb = (const char*)Bt;
#pragma unroll
  for (int kt = 0; kt < 2; kt++) {
#pragma unroll
    for (int i = 0; i < 4; i++) {
      int idx = i * 256 + tid;
      int r = idx >> 3;
      int c = (idx & 7) ^ (r & 7);
      gl2lds16(Ab + ((size_t)(m0 + r) * DIMD + kt * 64) * 2 + c * 16, (char*)As[kt] + idx * 16);
    }
#pragma unroll
    for (int i = 0; i < 2; i++) {
      int idx = i * 256 + tid;
      int r = idx >> 3;
      int c = (idx & 7) ^ (r & 7);
      gl2lds16(Bb + ((size_t)(n0 + r) * DIMD + kt * 64) * 2 + c * 16, (char*)Bs[kt] + idx * 16);
    }
  }

  f32x4 acc[4][2] = {};
  for (int kt = 0; kt < 8; kt++) {
    if (kt == 7) WAIT_BAR(0); else WAIT_BAR(6);
    if (kt < 6) {
      const int k0 = (kt + 2) * 64;
      const int buf2 = (kt + 2) % 3;
#pragma unroll
      for (int i = 0; i < 4; i++) {
        int idx = i * 256 + tid;
        int r = idx >> 3;
        int c = (idx & 7) ^ (r & 7);
        gl2lds16(Ab + ((size_t)(m0 + r) * DIMD + k0) * 2 + c * 16, (char*)As[buf2] + idx * 16);
      }
#pragma unroll
      for (int i = 0; i < 2; i++) {
        int idx = i * 256 + tid;
        int r = idx >> 3;
        int c = (idx & 7) ^ (r & 7);
        gl2lds16(Bb + ((size_t)(n0 + r) * DIMD + k0) * 2 + c * 16, (char*)Bs[buf2] + idx * 16);
      }
    }
    const int buf = kt % 3;
#pragma unroll
    for (int ks = 0; ks < 2; ks++) {
      bf16x8 av[4], bv[2];
#pragma unroll
      for (int i = 0; i < 4; i++)
        av[i] = *(const bf16x8*)&As[buf][(rw + i * 16 + row16) * 64 + (((ks * 4 + quad) ^ rho) * 8)];
#pragma unroll
      for (int j = 0; j < 2; j++)
        bv[j] = *(const bf16x8*)&Bs[buf][(cw + j * 16 + row16) * 64 + (((ks * 4 + quad) ^ rho) * 8)];
#pragma unroll
      for (int i = 0; i < 4; i++)
#pragma unroll
        for (int j = 0; j < 2; j++) acc[i][j] = MFMA16(av[i], bv[j], acc[i][j]);
    }
  }

#pragma unroll
  for (int j = 0; j < 2; j++) {
    const int col = n0 + cw + j * 16 + row16;
    const float bv = bias[col];
#pragma unroll
    for (int i = 0; i < 4; i++)
#pragma unroll
      for (int r = 0; r < 4; r++) {
        const int row = m0 + rw + i * 16 + quad * 4 + r;
        out[(size_t)row * DIMD + col] = acc[i][j][r] + bv;
      }
  }
}

extern "C" void kernel_launch(void* const* d_in, const int* in_sizes, int n_in,
                              void* d_out, int out_size, void* d_ws, size_t ws_size,
                              hipStream_t stream) {
  const float* x = (const float*)d_in[0];
  const int* mlab = (const int*)d_in[1];
  const float* gamma = (const float*)d_in[2];
  const float* beta = (const float*)d_in[3];
  const float* w_qkv = (const float*)d_in[4];
  const float* w_out = (const float*)d_in[5];
  const float* b_out = (const float*)d_in[6];
  float* out = (float*)d_out;

  char* ws = (char*)d_ws;
  unsigned short* xn = (unsigned short*)(ws);
  unsigned short* wqkvT = (unsigned short*)(ws + 8388608);
  unsigned short* woutT = (unsigned short*)(ws + 9961472);
  unsigned short* qbuf = (unsigned short*)(ws + 10485760);
  unsigned short* kbuf = (unsigned short*)(ws + 18874368);
  unsigned short* vtbuf = (unsigned short*)(ws + 27262976);
  unsigned short* aobuf = (unsigned short*)(ws + 35651584);

  prep_kernel<<<3072, 256, 0, stream>>>(x, gamma, beta, w_qkv, w_out, xn, wqkvT, woutT);
  qkv_gemm<<<dim3(64, 12), 256, 0, stream>>>(xn, wqkvT, qbuf, kbuf, vtbuf);
  attn_kernel<<<dim3(8, 32), 512, 0, stream>>>(qbuf, kbuf, vtbuf, mlab, aobuf);
  out_gemm<<<dim3(64, 8), 256, 0, stream>>>(aobuf, woutT, b_out, out);
}

// Round 11
// 154.847 us; speedup vs baseline: 1.0944x; 1.0944x over previous
//
#include <hip/hip_runtime.h>

#define DIMD 512
#define NTOK 2048
#define HEADS 8
#define DH 64

typedef __attribute__((ext_vector_type(4))) float f32x4;
typedef __attribute__((ext_vector_type(8))) __bf16 bf16x8;
typedef __attribute__((ext_vector_type(4))) short s16x4;

#define MFMA16(a, b, c) __builtin_amdgcn_mfma_f32_16x16x32_bf16((a), (b), (c), 0, 0, 0)
#define MFMAK16(a, b, c) __builtin_amdgcn_mfma_f32_16x16x16bf16_1k((a), (b), (c), 0, 0, 0)

__device__ __forceinline__ unsigned short f2bf(float f) {
  unsigned int u = __float_as_uint(f);
  u += 0x7fffu + ((u >> 16) & 1u);
  return (unsigned short)(u >> 16);
}

// raw hardware exp2: one v_exp_f32 (OCML exp2f is a multi-instr denorm-guarded
// sequence without -ffast-math — measured as the dominant attn VALU cost).
// Inputs here are <= -15 (live) or ~-1e5 (masked -> underflows to +0). Both exact.
__device__ __forceinline__ float fexp2(float x) {
  float r;
  asm("v_exp_f32 %0, %1" : "=v"(r) : "v"(x));
  return r;
}

// pack truncated bf16(b) into low short, bf16(a) into high short
__device__ __forceinline__ unsigned packhi(float b, float a) {
#if __has_builtin(__builtin_amdgcn_perm)
  return __builtin_amdgcn_perm(__float_as_uint(a), __float_as_uint(b), 0x07060302u);
#else
  return (__float_as_uint(b) >> 16) | (__float_as_uint(a) & 0xffff0000u);
#endif
}

// async global->LDS, 16B per lane; LDS dest = wave base + lane*16 (contiguous).
__device__ __forceinline__ void gl2lds16(const void* g, void* l) {
  auto gp = reinterpret_cast<__attribute__((address_space(1))) unsigned int*>(
      reinterpret_cast<unsigned long long>(g));
  auto lp = reinterpret_cast<__attribute__((address_space(3))) unsigned int*>(
      reinterpret_cast<unsigned long long>(l));
  __builtin_amdgcn_global_load_lds(gp, lp, 16, 0, 0);
}

// ---------------- prep: LN(bid<2048) + w_qkv transpose + w_out transpose ----------------
__global__ __launch_bounds__(256) void prep_kernel(const float* __restrict__ x,
                                                   const float* __restrict__ gamma,
                                                   const float* __restrict__ beta,
                                                   const float* __restrict__ w_qkv,
                                                   const float* __restrict__ w_out,
                                                   unsigned short* __restrict__ xn,
                                                   unsigned short* __restrict__ wqkvT,
                                                   unsigned short* __restrict__ woutT) {
  __shared__ float t[32][33];
  const int bid = blockIdx.x;
  if (bid < 2048) {
    const int row = bid * 4 + (threadIdx.x >> 6);
    const int lane = threadIdx.x & 63;
    const float4* xr = (const float4*)(x + (size_t)row * DIMD);
    float4 a = xr[lane];
    float4 b = xr[lane + 64];
    float s = a.x + a.y + a.z + a.w + b.x + b.y + b.z + b.w;
    for (int off = 1; off < 64; off <<= 1) s += __shfl_xor(s, off, 64);
    float mu = s * (1.0f / DIMD);
    float d0 = a.x - mu, d1 = a.y - mu, d2 = a.z - mu, d3 = a.w - mu;
    float e0 = b.x - mu, e1 = b.y - mu, e2 = b.z - mu, e3 = b.w - mu;
    float v = d0 * d0 + d1 * d1 + d2 * d2 + d3 * d3 + e0 * e0 + e1 * e1 + e2 * e2 + e3 * e3;
    for (int off = 1; off < 64; off <<= 1) v += __shfl_xor(v, off, 64);
    float rs = rsqrtf(v * (1.0f / DIMD) + 1e-5f);
    const float4* g4 = (const float4*)gamma;
    const float4* be4 = (const float4*)beta;
    float4 ga = g4[lane], gb = g4[lane + 64];
    float4 ba = be4[lane], bb = be4[lane + 64];
    unsigned p0 = (unsigned)f2bf(d0 * rs * ga.x + ba.x) | ((unsigned)f2bf(d1 * rs * ga.y + ba.y) << 16);
    unsigned p1 = (unsigned)f2bf(d2 * rs * ga.z + ba.z) | ((unsigned)f2bf(d3 * rs * ga.w + ba.w) << 16);
    unsigned p2 = (unsigned)f2bf(e0 * rs * gb.x + bb.x) | ((unsigned)f2bf(e1 * rs * gb.y + bb.y) << 16);
    unsigned p3 = (unsigned)f2bf(e2 * rs * gb.z + bb.z) | ((unsigned)f2bf(e3 * rs * gb.w + bb.w) << 16);
    uint2 w0; w0.x = p0; w0.y = p1;
    uint2 w1; w1.x = p2; w1.y = p3;
    *(uint2*)&xn[(size_t)row * DIMD + lane * 4] = w0;
    *(uint2*)&xn[(size_t)row * DIMD + 256 + lane * 4] = w1;
  } else {
    const float* w;
    unsigned short* wt;
    int C, bx, by;
    if (bid < 2816) { w = w_qkv; wt = wqkvT; C = 1536; bx = (bid - 2048) % 48; by = (bid - 2048) / 48; }
    else            { w = w_out; wt = woutT; C = 512;  bx = (bid - 2816) % 16; by = (bid - 2816) / 16; }
    const int R = 512;
    int tx = threadIdx.x & 31, ty = threadIdx.x >> 5;
    int c0 = bx * 32, r0 = by * 32;
    for (int i = 0; i < 4; i++)
      t[ty + 8 * i][tx] = w[(size_t)(r0 + ty + 8 * i) * C + c0 + tx];
    __syncthreads();
    for (int i = 0; i < 4; i++)
      wt[(size_t)(c0 + ty + 8 * i) * R + r0 + tx] = f2bf(t[tx][ty + 8 * i]);
  }
}

// ---------------- QKV GEMM: 128x128 tile, BK=64, swizzled DMA dbuf ----------------
__global__ __launch_bounds__(256, 2) void qkv_gemm(const unsigned short* __restrict__ A,
                                                   const unsigned short* __restrict__ Bt,
                                                   unsigned short* __restrict__ qb,
                                                   unsigned short* __restrict__ kb,
                                                   unsigned short* __restrict__ vtb) {
  __shared__ unsigned short As[2][128 * 64];
  __shared__ unsigned short Bs[2][128 * 64];
  const int tid = threadIdx.x;
  const int wave = tid >> 6, lane = tid & 63;
  const int row16 = lane & 15, quad = lane >> 4;
  const int rho = row16 & 7;
  const int m0 = blockIdx.x * 128;
  const int n0 = blockIdx.y * 128;
  const int rw = (wave & 1) * 64, cw = (wave >> 1) * 64;

  const char* Ab = (const char*)A;
  const char* Bb = (const char*)Bt;
#pragma unroll
  for (int i = 0; i < 4; i++) {
    int idx = i * 256 + tid;
    int r = idx >> 3;
    int c = (idx & 7) ^ (r & 7);
    gl2lds16(Ab + ((size_t)(m0 + r) * DIMD) * 2 + c * 16, (char*)As[0] + idx * 16);
    gl2lds16(Bb + ((size_t)(n0 + r) * DIMD) * 2 + c * 16, (char*)Bs[0] + idx * 16);
  }
  __syncthreads();

  f32x4 acc[4][4] = {};
  for (int kt = 0; kt < 8; kt++) {
    const int buf = kt & 1;
    if (kt < 7) {
      const int k0 = (kt + 1) * 64;
#pragma unroll
      for (int i = 0; i < 4; i++) {
        int idx = i * 256 + tid;
        int r = idx >> 3;
        int c = (idx & 7) ^ (r & 7);
        gl2lds16(Ab + ((size_t)(m0 + r) * DIMD + k0) * 2 + c * 16, (char*)As[buf ^ 1] + idx * 16);
        gl2lds16(Bb + ((size_t)(n0 + r) * DIMD + k0) * 2 + c * 16, (char*)Bs[buf ^ 1] + idx * 16);
      }
    }
#pragma unroll
    for (int ks = 0; ks < 2; ks++) {
      bf16x8 av[4], bv[4];
#pragma unroll
      for (int i = 0; i < 4; i++) {
        int Ra = rw + i * 16 + row16;
        int Rb = cw + i * 16 + row16;
        av[i] = *(const bf16x8*)&As[buf][Ra * 64 + (((ks * 4 + quad) ^ rho) * 8)];
        bv[i] = *(const bf16x8*)&Bs[buf][Rb * 64 + (((ks * 4 + quad) ^ rho) * 8)];
      }
#pragma unroll
      for (int i = 0; i < 4; i++)
#pragma unroll
        for (int j = 0; j < 4; j++) acc[i][j] = MFMA16(av[i], bv[j], acc[i][j]);
    }
    __syncthreads();
  }

  unsigned short* Ct = (unsigned short*)As;
#pragma unroll
  for (int i = 0; i < 4; i++)
#pragma unroll
    for (int j = 0; j < 4; j++)
#pragma unroll
      for (int r = 0; r < 4; r++)
        Ct[(rw + i * 16 + quad * 4 + r) * 136 + cw + j * 16 + row16] = f2bf(acc[i][j][r]);
  __syncthreads();

  const int sect = n0 >> 9;
  const int h0 = (n0 & 511) >> 6;
  const int b = m0 >> 11;
  const int nbase = m0 & 2047;
  if (sect < 2) {
    unsigned short* dst = (sect == 0) ? qb : kb;
#pragma unroll
    for (int i = 0; i < 8; i++) {
      int cid = i * 256 + tid;
      int row = cid >> 4, col0 = (cid & 15) * 8;
      int h = h0 + (col0 >> 6), d0 = col0 & 63;
      uint4 val = *(const uint4*)&Ct[row * 136 + col0];
      *(uint4*)&dst[(((size_t)(b * HEADS + h) * NTOK) + nbase + row) * DH + d0] = val;
    }
  } else {
#pragma unroll
    for (int u = 0; u < 4; u++) {
      int uid = u * 256 + tid;
      int col = uid >> 3, rc = (uid & 7) * 16;
      int h = h0 + (col >> 6), d = col & 63;
      unsigned short tmp[16];
#pragma unroll
      for (int j = 0; j < 16; j++) tmp[j] = Ct[(rc + j) * 136 + col];
      size_t base = ((size_t)(b * HEADS + h) * DH + d) * NTOK + nbase + rc;
      *(uint4*)&vtb[base] = *(uint4*)&tmp[0];
      *(uint4*)&vtb[base + 8] = *(uint4*)&tmp[8];
    }
  }
}

// ---------------- attention: q-tile 256 (8 waves), S^T + register PV, 1 barrier/tile ----------------
__global__ __launch_bounds__(512) void attn_kernel(const unsigned short* __restrict__ qb,
                                                   const unsigned short* __restrict__ kb,
                                                   const unsigned short* __restrict__ vtb,
                                                   const int* __restrict__ mlab,
                                                   unsigned short* __restrict__ ao) {
  __shared__ unsigned short Qs[256 * 64];     // 32KB
  __shared__ unsigned short Ks[2][64 * 64];   // 16KB
  __shared__ unsigned short Vs[2][64 * 64];   // 16KB
  const int tid = threadIdx.x;
  const int wave = tid >> 6, lane = tid & 63;
  const int row16 = lane & 15, quad = lane >> 4;
  const int rho = row16 & 7;
  const int bh = blockIdx.y;
  const int b = bh >> 3, h = bh & 7;
  const int q0 = blockIdx.x * 256;

  const char* qg = (const char*)(qb + ((size_t)bh * NTOK + q0) * DH);
  const char* kgb = (const char*)(kb + (size_t)bh * NTOK * DH);
  const char* vgb = (const char*)(vtb + (size_t)bh * DH * NTOK);
  const int sr = tid >> 3;              // 0..63 staging row
  const int sc = (tid & 7) ^ (sr & 7);  // swizzled source chunk

  // prologue: Q (256 rows) + K/V tile 0
#pragma unroll
  for (int i = 0; i < 4; i++)
    gl2lds16(qg + (sr + 64 * i) * 128 + sc * 16, (char*)Qs + tid * 16 + i * 8192);
  gl2lds16(kgb + sr * 128 + sc * 16, (char*)Ks[0] + tid * 16);
  gl2lds16(vgb + (size_t)sr * 4096 + sc * 16, (char*)Vs[0] + tid * 16);
  __syncthreads();

  // wave owns q-rows [wave*32, wave*32+32)
  bf16x8 aq[2][2];
#pragma unroll
  for (int qs = 0; qs < 2; qs++) {
    const int qrow = wave * 32 + qs * 16 + row16;
#pragma unroll
    for (int ki = 0; ki < 2; ki++)
      aq[qs][ki] = *(const bf16x8*)&Qs[qrow * 64 + (((ki * 4 + quad) ^ rho) * 8)];
  }

  f32x4 accT[4][2] = {};  // O^T frags: [d-group][q-group]
  float lsum[2] = {0.f, 0.f};
  const float cs = 0.125f * 1.44269504088896f;
  const float c0 = mlab[b * 4 + 0] ? -16.f : -100000.f;
  const float c1 = mlab[b * 4 + 1] ? -16.f : -100000.f;
  const float c2 = mlab[b * 4 + 2] ? -16.f : -100000.f;
  const float c3 = mlab[b * 4 + 3] ? -16.f : -100000.f;

  for (int t = 0; t < 32; t++) {
    const int buf = t & 1;
    if (t < 31) {
      gl2lds16(kgb + (size_t)(t + 1) * 8192 + sr * 128 + sc * 16, (char*)Ks[buf ^ 1] + tid * 16);
      gl2lds16(vgb + (size_t)(t + 1) * 128 + (size_t)sr * 4096 + sc * 16, (char*)Vs[buf ^ 1] + tid * 16);
    }
    // S'[key][q]: A = K frag, B = Q frag
    f32x4 S[2][4];
#pragma unroll
    for (int f = 0; f < 4; f++) {
      const unsigned short* Kr = &Ks[buf][(f * 16 + row16) * 64];
      bf16x8 ak0 = *(const bf16x8*)&Kr[(quad ^ rho) * 8];
      bf16x8 ak1 = *(const bf16x8*)&Kr[((quad + 4) ^ rho) * 8];
#pragma unroll
      for (int qs = 0; qs < 2; qs++) {
        f32x4 z = {};
        z = MFMA16(ak0, aq[qs][0], z);
        z = MFMA16(ak1, aq[qs][1], z);
        S[qs][f] = z;
      }
    }
    const int mi = t >> 3;
    const float c = (mi == 0) ? c0 : (mi == 1) ? c1 : (mi == 2) ? c2 : c3;
    // P' = exp2(S'*cs + c) via raw v_exp_f32; pack into K16 B-operand frags
    s16x4 pf[2][4];
#pragma unroll
    for (int qs = 0; qs < 2; qs++)
#pragma unroll
      for (int f = 0; f < 4; f++) {
        float p0 = fexp2(fmaf(S[qs][f][0], cs, c));
        float p1 = fexp2(fmaf(S[qs][f][1], cs, c));
        float p2 = fexp2(fmaf(S[qs][f][2], cs, c));
        float p3 = fexp2(fmaf(S[qs][f][3], cs, c));
        lsum[qs] += (p0 + p1) + (p2 + p3);
        uint2 pk;
        pk.x = packhi(p0, p1);
        pk.y = packhi(p2, p3);
        pf[qs][f] = *(s16x4*)&pk;
      }
    // O^T += V^T · P'
#pragma unroll
    for (int g = 0; g < 4; g++) {
      const unsigned short* Vr = &Vs[buf][(g * 16 + row16) * 64];
#pragma unroll
      for (int u = 0; u < 4; u++) {
        s16x4 va = *(const s16x4*)&Vr[(((2 * u + (quad >> 1)) ^ rho) * 8) + (quad & 1) * 4];
#pragma unroll
        for (int qs = 0; qs < 2; qs++) accT[g][qs] = MFMAK16(va, pf[qs][u], accT[g][qs]);
      }
    }
    __syncthreads();
  }

  // lane partial covers its quad's keys; combine across quads (q = qs*16+row16)
#pragma unroll
  for (int qs = 0; qs < 2; qs++) {
    float s = lsum[qs];
    s += __shfl_xor(s, 16, 64);
    s += __shfl_xor(s, 32, 64);
    lsum[qs] = 1.0f / s;
  }
#pragma unroll
  for (int qs = 0; qs < 2; qs++) {
    const int q = q0 + wave * 32 + qs * 16 + row16;
    unsigned short* aor = ao + ((size_t)b * NTOK + q) * DIMD + h * DH;
#pragma unroll
    for (int g = 0; g < 4; g++) {
      *(unsigned*)&aor[g * 16 + quad * 4] = packhi(accT[g][qs][0] * lsum[qs], accT[g][qs][1] * lsum[qs]);
      *(unsigned*)&aor[g * 16 + quad * 4 + 2] = packhi(accT[g][qs][2] * lsum[qs], accT[g][qs][3] * lsum[qs]);
    }
  }
}

// ---------------- out GEMM: 128x64 tile, DMA dbuf, fp32 out + bias ----------------
__global__ __launch_bounds__(256, 2) void out_gemm(const unsigned short* __restrict__ A,
                                                   const unsigned short* __restrict__ Bt,
                                                   const float* __restrict__ bias,
                                                   float* __restrict__ out) {
  __shared__ unsigned short As[2][128 * 64];
  __shared__ unsigned short Bs[2][64 * 64];
  const int tid = threadIdx.x;
  const int wave = tid >> 6, lane = tid & 63;
  const int row16 = lane & 15, quad = lane >> 4;
  const int rho = row16 & 7;
  const int m0 = blockIdx.x * 128;
  const int n0 = blockIdx.y * 64;
  const int rw = (wave & 1) * 64, cw = (wave >> 1) * 32;

  const char* Ab = (const char*)A;
  const char* Bb = (const char*)Bt;
#pragma unroll
  for (int i = 0; i < 4; i++) {
    int idx = i * 256 + tid;
    int r = idx >> 3;
    int c = (idx & 7) ^ (r & 7);
    gl2lds16(Ab + ((size_t)(m0 + r) * DIMD) * 2 + c * 16, (char*)As[0] + idx * 16);
  }
#pragma unroll
  for (int i = 0; i < 2; i++) {
    int idx = i * 256 + tid;
    int r = idx >> 3;
    int c = (idx & 7) ^ (r & 7);
    gl2lds16(Bb + ((size_t)(n0 + r) * DIMD) * 2 + c * 16, (char*)Bs[0] + idx * 16);
  }
  __syncthreads();

  f32x4 acc[4][2] = {};
  for (int kt = 0; kt < 8; kt++) {
    const int buf = kt & 1;
    if (kt < 7) {
      const int k0 = (kt + 1) * 64;
#pragma unroll
      for (int i = 0; i < 4; i++) {
        int idx = i * 256 + tid;
        int r = idx >> 3;
        int c = (idx & 7) ^ (r & 7);
        gl2lds16(Ab + ((size_t)(m0 + r) * DIMD + k0) * 2 + c * 16, (char*)As[buf ^ 1] + idx * 16);
      }
#pragma unroll
      for (int i = 0; i < 2; i++) {
        int idx = i * 256 + tid;
        int r = idx >> 3;
        int c = (idx & 7) ^ (r & 7);
        gl2lds16(Bb + ((size_t)(n0 + r) * DIMD + k0) * 2 + c * 16, (char*)Bs[buf ^ 1] + idx * 16);
      }
    }
#pragma unroll
    for (int ks = 0; ks < 2; ks++) {
      bf16x8 av[4], bv[2];
#pragma unroll
      for (int i = 0; i < 4; i++)
        av[i] = *(const bf16x8*)&As[buf][(rw + i * 16 + row16) * 64 + (((ks * 4 + quad) ^ rho) * 8)];
#pragma unroll
      for (int j = 0; j < 2; j++)
        bv[j] = *(const bf16x8*)&Bs[buf][(cw + j * 16 + row16) * 64 + (((ks * 4 + quad) ^ rho) * 8)];
#pragma unroll
      for (int i = 0; i < 4; i++)
#pragma unroll
        for (int j = 0; j < 2; j++) acc[i][j] = MFMA16(av[i], bv[j], acc[i][j]);
    }
    __syncthreads();
  }

#pragma unroll
  for (int j = 0; j < 2; j++) {
    const int col = n0 + cw + j * 16 + row16;
    const float bv = bias[col];
#pragma unroll
    for (int i = 0; i < 4; i++)
#pragma unroll
      for (int r = 0; r < 4; r++) {
        const int row = m0 + rw + i * 16 + quad * 4 + r;
        out[(size_t)row * DIMD + col] = acc[i][j][r] + bv;
      }
  }
}

extern "C" void kernel_launch(void* const* d_in, const int* in_sizes, int n_in,
                              void* d_out, int out_size, void* d_ws, size_t ws_size,
                              hipStream_t stream) {
  const float* x = (const float*)d_in[0];
  const int* mlab = (const int*)d_in[1];
  const float* gamma = (const float*)d_in[2];
  const float* beta = (const float*)d_in[3];
  const float* w_qkv = (const float*)d_in[4];
  const float* w_out = (const float*)d_in[5];
  const float* b_out = (const float*)d_in[6];
  float* out = (float*)d_out;

  char* ws = (char*)d_ws;
  unsigned short* xn = (unsigned short*)(ws);
  unsigned short* wqkvT = (unsigned short*)(ws + 8388608);
  unsigned short* woutT = (unsigned short*)(ws + 9961472);
  unsigned short* qbuf = (unsigned short*)(ws + 10485760);
  unsigned short* kbuf = (unsigned short*)(ws + 18874368);
  unsigned short* vtbuf = (unsigned short*)(ws + 27262976);
  unsigned short* aobuf = (unsigned short*)(ws + 35651584);

  prep_kernel<<<3072, 256, 0, stream>>>(x, gamma, beta, w_qkv, w_out, xn, wqkvT, woutT);
  qkv_gemm<<<dim3(64, 12), 256, 0, stream>>>(xn, wqkvT, qbuf, kbuf, vtbuf);
  attn_kernel<<<dim3(8, 32), 512, 0, stream>>>(qbuf, kbuf, vtbuf, mlab, aobuf);
  out_gemm<<<dim3(64, 8), 256, 0, stream>>>(aobuf, woutT, b_out, out);
}